// Round 11
// baseline (140.781 us; speedup 1.0000x reference)
//
#include <hip/hip_runtime.h>
#include <hip/hip_bf16.h>
#include <stdint.h>

// Problem constants
#define MB 8192     // batch (rows and cols of sim)
#define KD 256      // embedding dim
#define BM 128      // rows per block (2x2 waves, each 64 rows x 32 cols)
#define BN 64       // cols per chunk
#define NSPLIT 8    // column slabs (512 blocks: proven-good L2 behavior, 18.7MB fetch)
#define SLAB (MB / NSPLIT)   // 1024 cols per slab
#define NCHUNK (SLAB / BN)   // 16 chunks per slab
#define VOCAB 1000000
#define COFF 104.0f          // fixed exp offset (overflow/underflow-safe)
#define LOG2E 1.44269504088896340736f

typedef __attribute__((ext_vector_type(8))) short bf16x8;
typedef __attribute__((ext_vector_type(4))) float f32x4;

__device__ __forceinline__ unsigned short f2bf(float x) {
  union { float f; uint32_t u; } v; v.f = x;
  uint32_t r = v.u + 0x7fffu + ((v.u >> 16) & 1u);   // RNE
  return (unsigned short)(r >> 16);
}

__device__ __forceinline__ float fast_exp2(float x) {
#if __has_builtin(__builtin_amdgcn_exp2f)
  return __builtin_amdgcn_exp2f(x);
#else
  return exp2f(x);
#endif
}

// async global->LDS DMA, 16B per lane, LDS dest = wave-uniform base + lane*16
#define GLOAD_LDS16(g, l)                                                      \
  __builtin_amdgcn_global_load_lds(                                            \
      (const __attribute__((address_space(1))) void*)(g),                      \
      (__attribute__((address_space(3))) void*)(l), 16, 0, 0)

// ---- convert fp32->bf16 for A,B + pos_sim (fp32, wave per row) + zero hist ----
__global__ __launch_bounds__(256) void convertpos_kernel(
    const float* __restrict__ A, const float* __restrict__ B,
    unsigned short* __restrict__ Abf, unsigned short* __restrict__ Bbf,
    float* __restrict__ pos, int* __restrict__ hist) {
  int t = blockIdx.x * 256 + threadIdx.x;        // 524288 threads, 1 float4 each
  const float4 a = ((const float4*)A)[t];
  const float4 b = ((const float4*)B)[t];
  ushort4 oa, ob;
  oa.x = f2bf(a.x); oa.y = f2bf(a.y); oa.z = f2bf(a.z); oa.w = f2bf(a.w);
  ob.x = f2bf(b.x); ob.y = f2bf(b.y); ob.z = f2bf(b.z); ob.w = f2bf(b.w);
  ((ushort4*)Abf)[t] = oa;
  ((ushort4*)Bbf)[t] = ob;
  // pos_sim: wave (t>>6) == row, 64 lanes cover KD/4 float4 chunks
  float d = a.x * b.x + a.y * b.y + a.z * b.z + a.w * b.w;
  #pragma unroll
  for (int off = 32; off; off >>= 1) d += __shfl_down(d, off, 64);
  if ((threadIdx.x & 63) == 0) pos[t >> 6] = d;
  // zero the vocab histogram (1M ints == 524288 uint2)
  ((uint2*)hist)[t] = make_uint2(0u, 0u);
}

// ---- histogram of ids + b2 = -(log2 q + C*log2e) + zero accumulators ----
__global__ __launch_bounds__(256) void histb2_kernel(
    const int* __restrict__ ids, const float* __restrict__ q,
    int* __restrict__ hist, float* __restrict__ b2,
    float* __restrict__ ps, float* __restrict__ out) {
  int i = blockIdx.x * 256 + threadIdx.x;   // 32 blocks -> 8192 threads
  atomicAdd(&hist[ids[i]], 1);
  // exp(sim - ln q - C) == exp2(sim*LOG2E + b2), b2 = -(log2 q + C*LOG2E)
  b2[i] = -(log2f(q[i]) + COFF * LOG2E);
  ps[i] = 0.0f;
  if (i == 0) out[0] = 0.0f;
}

// ---- fused GEMM + masked fixed-offset exp-sum, 2-phase dbuf, 2x2 wave tile ----
__global__ __launch_bounds__(256, 2) void fused_kernel(
    const unsigned short* __restrict__ Abf,
    const unsigned short* __restrict__ Bbf,
    const int* __restrict__ ids,
    const float* __restrict__ b2,
    float* __restrict__ ps) {
  const int slab = blockIdx.y;
  const int tid = threadIdx.x;
  const int wave = tid >> 6;
  const int wr = wave >> 1;                  // wave row-tile (0..1): 64 rows each
  const int wc = wave & 1;                   // wave col-tile (0..1): 32 cols each
  const int lane = tid & 63;
  const int quad = lane >> 4;
  const int lpos = lane & 15;
  const int rowbase = blockIdx.x * BM + wr * 64;
  const int colbase = slab * SLAB;

  // Fragment-ordered B staging, DOUBLE buffered: cell c = ((ct*8+kb)*4+quad)*16+lpos
  // holds B[col = ct*16+lpos][k = kb*32+quad*8 .. +8). Linear in c == tid + s8*256,
  // matching global_load_lds's uniform-base+lane*16 dest. Frag reads wave-linear
  // (lane i -> byte 16*i) => conflict-free ds_read_b128. Wave (wr,wc) reads only
  // its ct pair {wc*2, wc*2+1} => block LDS-read volume = 2x tile (was 4x).
  __shared__ unsigned short Bs[2][2048 * 8];   // 2 x 32 KB (2 blocks/CU -> 128 KB)

  // A fragments resident: wave owns rows [rowbase, rowbase+64)
  bf16x8 afrag[4][8];
  #pragma unroll
  for (int rt = 0; rt < 4; ++rt)
    #pragma unroll
    for (int kb = 0; kb < 8; ++kb)
      afrag[rt][kb] = *(const bf16x8*)(Abf + (rowbase + rt * 16 + lpos) * KD + kb * 32 + quad * 8);

  // chunk-invariant staging addresses (advance global side by chunk*BN*KD)
  const unsigned short* gsrc[8];
  int ldso[8];                               // short-offset within one buffer
  #pragma unroll
  for (int s8 = 0; s8 < 8; ++s8) {
    int c = tid + s8 * 256;
    int lp = c & 15, qd = (c >> 4) & 3, kb = (c >> 6) & 7, ct = c >> 9;
    gsrc[s8] = Bbf + (colbase + ct * 16 + lp) * KD + kb * 32 + qd * 8;
    ldso[s8] = c * 8;
  }

  int idr[4][4];
  float srun[4][4];
  #pragma unroll
  for (int rt = 0; rt < 4; ++rt)
    #pragma unroll
    for (int r = 0; r < 4; ++r) {
      idr[rt][r] = ids[rowbase + rt * 16 + quad * 4 + r];
      srun[rt][r] = 0.0f;
    }

  // Prologue: prefetch ids/b2 (this wave's ct pair) + B-tile for chunk 0
  int idv[2][2];
  float bv[2][2];
  #pragma unroll
  for (int ctl = 0; ctl < 2; ++ctl) {
    idv[0][ctl] = ids[colbase + (wc * 2 + ctl) * 16 + lpos];
    bv[0][ctl]  = b2 [colbase + (wc * 2 + ctl) * 16 + lpos];
  }
  #pragma unroll
  for (int s8 = 0; s8 < 8; ++s8)
    GLOAD_LDS16(gsrc[s8], &Bs[0][0] + ldso[s8]);
  __syncthreads();                           // drains vmcnt(0): chunk 0 ready

  // Per iteration: issue next-chunk ids/b2 loads FIRST (so their vmcnt retires
  // before the DMAs'), then next-chunk DMA, then compute current chunk from
  // registers+LDS only. End-of-body __syncthreads() drains the prefetch --
  // its latency hid under the MFMA+exp compute phase.
#define FUSED_BODY(T, CUR)                                                     \
  {                                                                            \
    const int nxt = (T) + 1;                                                   \
    if (nxt < NCHUNK) {                                                        \
      _Pragma("unroll")                                                        \
      for (int ctl = 0; ctl < 2; ++ctl) {                                      \
        idv[(CUR) ^ 1][ctl] = ids[colbase + nxt * BN + (wc * 2 + ctl) * 16 + lpos]; \
        bv[(CUR) ^ 1][ctl]  = b2 [colbase + nxt * BN + (wc * 2 + ctl) * 16 + lpos]; \
      }                                                                        \
      _Pragma("unroll")                                                        \
      for (int s8 = 0; s8 < 8; ++s8)                                           \
        GLOAD_LDS16(gsrc[s8] + nxt * (BN * KD), &Bs[(CUR) ^ 1][0] + ldso[s8]); \
    }                                                                          \
    _Pragma("unroll")                                                          \
    for (int ctl = 0; ctl < 2; ++ctl) {                                        \
      const int ct = wc * 2 + ctl;                                             \
      const unsigned short* bp = &Bs[CUR][0] + (ct * 512 + quad * 16 + lpos) * 8; \
      bf16x8 bfrag[8];                                                         \
      _Pragma("unroll")                                                        \
      for (int kb = 0; kb < 8; ++kb)                                           \
        bfrag[kb] = *(const bf16x8*)(bp + kb * 512);                           \
      const int idj = idv[CUR][ctl];                                           \
      const float bj = bv[CUR][ctl];                                           \
      _Pragma("unroll")                                                        \
      for (int rt = 0; rt < 4; ++rt) {                                         \
        f32x4 acc = {0.0f, 0.0f, 0.0f, 0.0f};                                  \
        _Pragma("unroll")                                                      \
        for (int kb = 0; kb < 8; ++kb)                                         \
          acc = __builtin_amdgcn_mfma_f32_16x16x32_bf16(afrag[rt][kb], bfrag[kb], acc, 0, 0, 0); \
        _Pragma("unroll")                                                      \
        for (int r = 0; r < 4; ++r) {                                          \
          const float e = fast_exp2(__builtin_fmaf(acc[r], LOG2E, bj));        \
          srun[rt][r] += (idj != idr[rt][r]) ? e : 0.0f;                       \
        }                                                                      \
      }                                                                        \
    }                                                                          \
    __syncthreads();                                                           \
  }

  for (int t2 = 0; t2 < NCHUNK; t2 += 2) {
    FUSED_BODY(t2, 0)
    FUSED_BODY(t2 + 1, 1)
  }
#undef FUSED_BODY

  // sum across the 16 lanes of each quad (the 16 columns of the frag).
  // Waves (wr,0) and (wr,1) cover different cols of the same rows -> both
  // atomicAdd into ps[row] (2 atomics/row/block; 16 total/row across slabs).
  #pragma unroll
  for (int rt = 0; rt < 4; ++rt)
    #pragma unroll
    for (int r = 0; r < 4; ++r) {
      float v = srun[rt][r];
      #pragma unroll
      for (int off = 1; off < 16; off <<= 1) v += __shfl_xor(v, off, 64);
      if (lpos == 0)
        atomicAdd(&ps[rowbase + rt * 16 + quad * 4 + r], v);
    }
}

// ---- finalize: per-row loss, mean ----
__global__ __launch_bounds__(256) void finalize_kernel(
    const float* __restrict__ ps, const float* __restrict__ pos,
    const float* __restrict__ q, const int* __restrict__ ids,
    const int* __restrict__ hist, float* __restrict__ out) {
  int i = blockIdx.x * 256 + threadIdx.x;   // 32 blocks -> 8192 threads
  const float s = ps[i];
  const float nm = (float)(MB - hist[ids[i]]);
  // log S_i = log(s) + C + log(1-q_i) - log(n_miss)
  const float z = logf(s) + COFF + logf(1.0f - q[i]) - logf(nm);
  const float p = pos[i];
  const float hi = fmaxf(p, z), lo = fminf(p, z);
  float loss = -p + hi + log1pf(__expf(lo - hi));

  #pragma unroll
  for (int off = 32; off; off >>= 1) loss += __shfl_down(loss, off, 64);
  __shared__ float red[4];
  if ((threadIdx.x & 63) == 0) red[threadIdx.x >> 6] = loss;
  __syncthreads();
  if (threadIdx.x == 0) {
    float t = red[0] + red[1] + red[2] + red[3];
    atomicAdd(out, t * (1.0f / (float)MB));
  }
}

extern "C" void kernel_launch(void* const* d_in, const int* in_sizes, int n_in,
                              void* d_out, int out_size, void* d_ws, size_t ws_size,
                              hipStream_t stream) {
  (void)in_sizes; (void)n_in; (void)out_size; (void)ws_size;
  const float* input_emb  = (const float*)d_in[0];
  const float* target_emb = (const float*)d_in[1];
  const int*   target_ids = (const int*)d_in[2];
  const float* q_probas   = (const float*)d_in[3];
  float* out = (float*)d_out;

  char* ws = (char*)d_ws;
  unsigned short* Abf = (unsigned short*)(ws);                    // 4 MB
  unsigned short* Bbf = (unsigned short*)(ws + (4u << 20));       // 4 MB
  int*   hist = (int*)  (ws + (8u << 20));                        // 4 MB
  float* b2   = (float*)(ws + (12u << 20));                       // 32 KB
  float* pos  = (float*)(ws + (12u << 20) + 32768);               // 32 KB
  float* ps   = (float*)(ws + (12u << 20) + 65536);               // 32 KB

  convertpos_kernel<<<2048, 256, 0, stream>>>(input_emb, target_emb, Abf, Bbf, pos, hist);
  histb2_kernel<<<32, 256, 0, stream>>>(target_ids, q_probas, hist, b2, ps, out);
  fused_kernel<<<dim3(MB / BM, NSPLIT), 256, 0, stream>>>(Abf, Bbf, target_ids, b2, ps);
  finalize_kernel<<<32, 256, 0, stream>>>(ps, pos, q_probas, target_ids, hist, out);
}

// Round 15
// 122.352 us; speedup vs baseline: 1.1506x; 1.1506x over previous
//
#include <hip/hip_runtime.h>
#include <hip/hip_bf16.h>
#include <stdint.h>

// Problem constants
#define MB 8192     // batch (rows and cols of sim)
#define KD 256      // embedding dim
#define BM 128      // rows per block (2x2 waves, each 64 rows x 32 cols)
#define BN 64       // cols per chunk
#define NSPLIT 8    // column slabs (512 blocks: proven-good L2 behavior)
#define SLAB (MB / NSPLIT)   // 1024 cols per slab
#define NCHUNK (SLAB / BN)   // 16 chunks per slab
#define VOCAB 1000000
#define COFF 104.0f          // fixed exp offset (overflow/underflow-safe)
#define LOG2E 1.44269504088896340736f

typedef __attribute__((ext_vector_type(8))) short bf16x8;
typedef __attribute__((ext_vector_type(4))) float f32x4;

__device__ __forceinline__ unsigned short f2bf(float x) {
  union { float f; uint32_t u; } v; v.f = x;
  uint32_t r = v.u + 0x7fffu + ((v.u >> 16) & 1u);   // RNE
  return (unsigned short)(r >> 16);
}

__device__ __forceinline__ float fast_exp2(float x) {
#if __has_builtin(__builtin_amdgcn_exp2f)
  return __builtin_amdgcn_exp2f(x);
#else
  return exp2f(x);
#endif
}

// async global->LDS DMA, 16B per lane, LDS dest = wave-uniform base + lane*16
#define GLOAD_LDS16(g, l)                                                      \
  __builtin_amdgcn_global_load_lds(                                            \
      (const __attribute__((address_space(1))) void*)(g),                      \
      (__attribute__((address_space(3))) void*)(l), 16, 0, 0)

// ---- convert fp32->bf16 for A,B + pos_sim (fp32, wave per row) + zero hist ----
__global__ __launch_bounds__(256) void convertpos_kernel(
    const float* __restrict__ A, const float* __restrict__ B,
    unsigned short* __restrict__ Abf, unsigned short* __restrict__ Bbf,
    float* __restrict__ pos, int* __restrict__ hist) {
  int t = blockIdx.x * 256 + threadIdx.x;        // 524288 threads, 1 float4 each
  const float4 a = ((const float4*)A)[t];
  const float4 b = ((const float4*)B)[t];
  ushort4 oa, ob;
  oa.x = f2bf(a.x); oa.y = f2bf(a.y); oa.z = f2bf(a.z); oa.w = f2bf(a.w);
  ob.x = f2bf(b.x); ob.y = f2bf(b.y); ob.z = f2bf(b.z); ob.w = f2bf(b.w);
  ((ushort4*)Abf)[t] = oa;
  ((ushort4*)Bbf)[t] = ob;
  // pos_sim: wave (t>>6) == row, 64 lanes cover KD/4 float4 chunks
  float d = a.x * b.x + a.y * b.y + a.z * b.z + a.w * b.w;
  #pragma unroll
  for (int off = 32; off; off >>= 1) d += __shfl_down(d, off, 64);
  if ((threadIdx.x & 63) == 0) pos[t >> 6] = d;
  // zero the vocab histogram (1M ints == 524288 uint2)
  ((uint2*)hist)[t] = make_uint2(0u, 0u);
}

// ---- histogram of ids + b2 = -(log2 q + C*log2e) + zero accumulators ----
__global__ __launch_bounds__(256) void histb2_kernel(
    const int* __restrict__ ids, const float* __restrict__ q,
    int* __restrict__ hist, float* __restrict__ b2,
    float* __restrict__ ps, float* __restrict__ out) {
  int i = blockIdx.x * 256 + threadIdx.x;   // 32 blocks -> 8192 threads
  atomicAdd(&hist[ids[i]], 1);
  // exp(sim - ln q - C) == exp2(sim*LOG2E + b2), b2 = -(log2 q + C*LOG2E)
  b2[i] = -(log2f(q[i]) + COFF * LOG2E);
  ps[i] = 0.0f;
  if (i == 0) out[0] = 0.0f;
}

// ---- fused GEMM + masked fixed-offset exp-sum ----
// 2-phase dbuf, 2x2 wave tile (64 rows x 32 cols per wave), register-trimmed:
//  - ids/b2 slab tables live in LDS (no vmem in compute phase, no reg dbuf)
//  - staging addresses are affine in s8: one base pointer, inline offsets
__global__ __launch_bounds__(256, 2) void fused_kernel(
    const unsigned short* __restrict__ Abf,
    const unsigned short* __restrict__ Bbf,
    const int* __restrict__ ids,
    const float* __restrict__ b2,
    float* __restrict__ ps) {
  const int slab = blockIdx.y;
  const int tid = threadIdx.x;
  const int wave = tid >> 6;
  const int wr = wave >> 1;                  // wave row-tile (0..1): 64 rows each
  const int wc = wave & 1;                   // wave col-tile (0..1): 32 cols each
  const int lane = tid & 63;
  const int quad = lane >> 4;
  const int lpos = lane & 15;
  const int rowbase = blockIdx.x * BM + wr * 64;
  const int colbase = slab * SLAB;

  // Fragment-ordered B staging, DOUBLE buffered: cell c = ((ct*8+kb)*4+quad)*16+lpos
  // holds B[col = ct*16+lpos][k = kb*32+quad*8 .. +8). Linear in c == tid + s8*256,
  // matching global_load_lds's uniform-base+lane*16 dest. Frag reads wave-linear
  // (lane i -> byte 16*i) => conflict-free ds_read_b128. Wave (wr,wc) reads only
  // its ct pair {wc*2, wc*2+1} => block LDS-read volume = 2x tile (was 4x in 1-D).
  __shared__ unsigned short Bs[2][2048 * 8];   // 64 KB
  __shared__ int   ids_s[SLAB];                // 4 KB (slab-constant)
  __shared__ float b2_s[SLAB];                 // 4 KB (slab-constant)

  // slab tables: 1024 entries, 4 per thread, coalesced 16B loads
  const int4   tiv = ((const int4*)(ids + colbase))[tid];
  const float4 tbv = ((const float4*)(b2 + colbase))[tid];

  // A fragments resident: wave owns rows [rowbase, rowbase+64)  (128 VGPRs)
  bf16x8 afrag[4][8];
  #pragma unroll
  for (int rt = 0; rt < 4; ++rt)
    #pragma unroll
    for (int kb = 0; kb < 8; ++kb)
      afrag[rt][kb] = *(const bf16x8*)(Abf + (rowbase + rt * 16 + lpos) * KD + kb * 32 + quad * 8);

  // Affine staging addresses (c = tid + s8*256):
  //   lp=tid&15, qd=(tid>>4)&3, kb=(tid>>6)&3 | (s8&1)<<2, ct=s8>>1
  //   global off = gbase + (s8>>1)*4096 + (s8&1)*128 + chunk*BN*KD   [shorts]
  //   LDS off    = tid*8 + s8*2048                                   [shorts]
  const unsigned short* gbase =
      Bbf + (colbase + (tid & 15)) * KD + ((tid >> 6) & 3) * 32 + ((tid >> 4) & 3) * 8;

#define STAGE(T, BUF)                                                          \
  _Pragma("unroll")                                                            \
  for (int s8 = 0; s8 < 8; ++s8)                                               \
    GLOAD_LDS16(gbase + (T) * (BN * KD) + (s8 >> 1) * 4096 + (s8 & 1) * 128,   \
                &Bs[BUF][0] + tid * 8 + s8 * 2048);

  int idr[4][4];
  float srun[4][4];
  #pragma unroll
  for (int rt = 0; rt < 4; ++rt)
    #pragma unroll
    for (int r = 0; r < 4; ++r) {
      idr[rt][r] = ids[rowbase + rt * 16 + quad * 4 + r];
      srun[rt][r] = 0.0f;
    }

  // Prologue: stage chunk 0, park slab tables in LDS, barrier (drains vmcnt).
  STAGE(0, 0)
  ((int4*)ids_s)[tid] = tiv;
  ((float4*)b2_s)[tid] = tbv;
  __syncthreads();                           // chunk 0 + tables ready

  // Per iteration: issue next-chunk DMA first, then compute current chunk from
  // registers+LDS only (tables are LDS -> lgkmcnt, independent of DMA vmcnt).
  // End-of-body __syncthreads() drains the prefetch, hidden under MFMA+exp.
#define FUSED_BODY(T, CUR)                                                     \
  {                                                                            \
    if ((T) + 1 < NCHUNK) { STAGE((T) + 1, (CUR) ^ 1) }                        \
    _Pragma("unroll")                                                          \
    for (int ctl = 0; ctl < 2; ++ctl) {                                        \
      const int ct = wc * 2 + ctl;                                             \
      const int jloc = (T) * BN + ct * 16 + lpos;                              \
      const int idj = ids_s[jloc];                                             \
      const float bj = b2_s[jloc];                                             \
      const unsigned short* bp = &Bs[CUR][0] + (ct * 512 + lane) * 8;          \
      bf16x8 bfrag[8];                                                         \
      _Pragma("unroll")                                                        \
      for (int kb = 0; kb < 8; ++kb)                                           \
        bfrag[kb] = *(const bf16x8*)(bp + kb * 512);                           \
      _Pragma("unroll")                                                        \
      for (int rt = 0; rt < 4; ++rt) {                                         \
        f32x4 acc = {0.0f, 0.0f, 0.0f, 0.0f};                                  \
        _Pragma("unroll")                                                      \
        for (int kb = 0; kb < 8; ++kb)                                         \
          acc = __builtin_amdgcn_mfma_f32_16x16x32_bf16(afrag[rt][kb], bfrag[kb], acc, 0, 0, 0); \
        _Pragma("unroll")                                                      \
        for (int r = 0; r < 4; ++r) {                                          \
          const float e = fast_exp2(__builtin_fmaf(acc[r], LOG2E, bj));        \
          srun[rt][r] += (idj != idr[rt][r]) ? e : 0.0f;                       \
        }                                                                      \
      }                                                                        \
    }                                                                          \
    __syncthreads();                                                           \
  }

  for (int t2 = 0; t2 < NCHUNK; t2 += 2) {
    FUSED_BODY(t2, 0)
    FUSED_BODY(t2 + 1, 1)
  }
#undef FUSED_BODY
#undef STAGE

  // sum across the 16 lanes of each quad (the 16 columns of the frag).
  // Waves (wr,0) and (wr,1) cover different cols of the same rows -> both
  // atomicAdd into ps[row] (2 atomics/row/block).
  #pragma unroll
  for (int rt = 0; rt < 4; ++rt)
    #pragma unroll
    for (int r = 0; r < 4; ++r) {
      float v = srun[rt][r];
      #pragma unroll
      for (int off = 1; off < 16; off <<= 1) v += __shfl_xor(v, off, 64);
      if (lpos == 0)
        atomicAdd(&ps[rowbase + rt * 16 + quad * 4 + r], v);
    }
}

// ---- finalize: per-row loss, mean ----
__global__ __launch_bounds__(256) void finalize_kernel(
    const float* __restrict__ ps, const float* __restrict__ pos,
    const float* __restrict__ q, const int* __restrict__ ids,
    const int* __restrict__ hist, float* __restrict__ out) {
  int i = blockIdx.x * 256 + threadIdx.x;   // 32 blocks -> 8192 threads
  const float s = ps[i];
  const float nm = (float)(MB - hist[ids[i]]);
  // log S_i = log(s) + C + log(1-q_i) - log(n_miss)
  const float z = logf(s) + COFF + logf(1.0f - q[i]) - logf(nm);
  const float p = pos[i];
  const float hi = fmaxf(p, z), lo = fminf(p, z);
  float loss = -p + hi + log1pf(__expf(lo - hi));

  #pragma unroll
  for (int off = 32; off; off >>= 1) loss += __shfl_down(loss, off, 64);
  __shared__ float red[4];
  if ((threadIdx.x & 63) == 0) red[threadIdx.x >> 6] = loss;
  __syncthreads();
  if (threadIdx.x == 0) {
    float t = red[0] + red[1] + red[2] + red[3];
    atomicAdd(out, t * (1.0f / (float)MB));
  }
}

extern "C" void kernel_launch(void* const* d_in, const int* in_sizes, int n_in,
                              void* d_out, int out_size, void* d_ws, size_t ws_size,
                              hipStream_t stream) {
  (void)in_sizes; (void)n_in; (void)out_size; (void)ws_size;
  const float* input_emb  = (const float*)d_in[0];
  const float* target_emb = (const float*)d_in[1];
  const int*   target_ids = (const int*)d_in[2];
  const float* q_probas   = (const float*)d_in[3];
  float* out = (float*)d_out;

  char* ws = (char*)d_ws;
  unsigned short* Abf = (unsigned short*)(ws);                    // 4 MB
  unsigned short* Bbf = (unsigned short*)(ws + (4u << 20));       // 4 MB
  int*   hist = (int*)  (ws + (8u << 20));                        // 4 MB
  float* b2   = (float*)(ws + (12u << 20));                       // 32 KB
  float* pos  = (float*)(ws + (12u << 20) + 32768);               // 32 KB
  float* ps   = (float*)(ws + (12u << 20) + 65536);               // 32 KB

  convertpos_kernel<<<2048, 256, 0, stream>>>(input_emb, target_emb, Abf, Bbf, pos, hist);
  histb2_kernel<<<32, 256, 0, stream>>>(target_ids, q_probas, hist, b2, ps, out);
  fused_kernel<<<dim3(MB / BM, NSPLIT), 256, 0, stream>>>(Abf, Bbf, target_ids, b2, ps);
  finalize_kernel<<<32, 256, 0, stream>>>(ps, pos, q_probas, target_ids, hist, out);
}